// Round 2
// baseline (1322.875 us; speedup 1.0000x reference)
//
#include <hip/hip_runtime.h>
#include <hip/hip_bf16.h>

#define FEAT 128

// ---- CSR build -------------------------------------------------------------

__global__ void hist_kernel(const int* __restrict__ dst, int* __restrict__ counts, int E) {
    int e = blockIdx.x * 256 + threadIdx.x;
    if (e < E) atomicAdd(&counts[dst[e]], 1);
}

__global__ __launch_bounds__(1024)
void scan_kernel(const int* __restrict__ counts, int* __restrict__ indptr,
                 int* __restrict__ cursor, float* __restrict__ dinv, int n, int E) {
    __shared__ int swave[16];
    __shared__ int s_carry;
    int tid = threadIdx.x, lane = tid & 63, wid = tid >> 6;
    if (tid == 0) s_carry = 0;
    __syncthreads();
    for (int base = 0; base < n; base += 1024) {
        int i = base + tid;
        int v = (i < n) ? counts[i] : 0;
        int x = v;
        #pragma unroll
        for (int off = 1; off < 64; off <<= 1) {
            int y = __shfl_up(x, off);
            if (lane >= off) x += y;
        }
        if (lane == 63) swave[wid] = x;
        __syncthreads();
        if (wid == 0 && lane < 16) {
            int s = swave[lane];
            #pragma unroll
            for (int off = 1; off < 16; off <<= 1) {
                int y = __shfl_up(s, off);
                if (lane >= off) s += y;
            }
            swave[lane] = s;
        }
        __syncthreads();
        int waveoff = (wid > 0) ? swave[wid - 1] : 0;
        int carry = s_carry;
        if (i < n) {
            int excl = carry + waveoff + x - v;
            indptr[i] = excl;
            cursor[i] = excl;
            dinv[i]   = rsqrtf((float)(v + 1));
        }
        __syncthreads();
        if (tid == 1023) s_carry = carry + swave[15];
        __syncthreads();
    }
    if (threadIdx.x == 0) indptr[n] = E;
}

__global__ void fill_kernel(const int* __restrict__ src, const int* __restrict__ dst,
                            int* __restrict__ cursor, int* __restrict__ ssrc, int E) {
    int e = blockIdx.x * 256 + threadIdx.x;
    if (e < E) {
        int d = dst[e];
        int pos = atomicAdd(&cursor[d], 1);
        ssrc[pos] = src[e];
    }
}

// ---- GEMM (fp32 vector ALU): hs[row] = (in[row] @ W) * dinv[row] -----------
// block (32,8): ty = row-within-block, tx picks a float4 of columns.

__global__ __launch_bounds__(256)
void gemm_f32(const float* __restrict__ in, const float* __restrict__ W,
              const float* __restrict__ dinv, float* __restrict__ hs, int n) {
    __shared__ float xs[8][128];
    int tx = threadIdx.x;       // 0..31
    int ty = threadIdx.y;       // 0..7
    int row = blockIdx.x * 8 + ty;

    // stage the 8 input rows in LDS
    float4 xv = ((const float4*)(in + (size_t)row * FEAT))[tx];
    *(float4*)&xs[ty][tx * 4] = xv;
    __syncthreads();

    const float4* Wv = (const float4*)W;   // W[k][c], float4 over c
    float4 acc = {0.f, 0.f, 0.f, 0.f};
    #pragma unroll
    for (int k0 = 0; k0 < FEAT; k0 += 8) {
        #pragma unroll
        for (int kk = 0; kk < 8; ++kk) {
            float xk = xs[ty][k0 + kk];
            float4 wv = Wv[(k0 + kk) * 32 + tx];
            acc.x += xk * wv.x;
            acc.y += xk * wv.y;
            acc.z += xk * wv.z;
            acc.w += xk * wv.w;
        }
    }

    float d = dinv[row];
    acc.x *= d; acc.y *= d; acc.z *= d; acc.w *= d;
    ((float4*)(hs + (size_t)row * FEAT))[tx] = acc;
}

// ---- aggregation: out[i] = act( dinv[i] * (hs[i] + sum_{e: dst=i} hs[src_e]) + b )

__global__ __launch_bounds__(256)
void agg_kernel(const float* __restrict__ hs, const int* __restrict__ indptr,
                const int* __restrict__ ssrc, const float* __restrict__ dinv,
                const float* __restrict__ bias, float* __restrict__ out,
                int n, int do_relu) {
    int wid = threadIdx.x >> 6, lane = threadIdx.x & 63;
    int node = blockIdx.x * 4 + wid;
    if (node >= n) return;

    const float2* hs2 = (const float2*)hs;
    float2 acc = hs2[(size_t)node * 64 + lane];   // self-loop term (pre-scaled by dinv[node])

    int start = indptr[node], end = indptr[node + 1];
    for (int e0 = start; e0 < end; e0 += 64) {
        int cnt = end - e0;
        if (cnt > 64) cnt = 64;
        int sv = (lane < cnt) ? ssrc[e0 + lane] : 0;
        for (int j = 0; j < cnt; ++j) {
            int s = __shfl(sv, j);
            float2 v = hs2[(size_t)s * 64 + lane];
            acc.x += v.x;
            acc.y += v.y;
        }
    }

    float d = dinv[node];
    float2 bv = ((const float2*)bias)[lane];
    float ox = acc.x * d + bv.x;
    float oy = acc.y * d + bv.y;
    if (do_relu) { ox = fmaxf(ox, 0.f); oy = fmaxf(oy, 0.f); }
    float2 o; o.x = ox; o.y = oy;
    ((float2*)out)[(size_t)node * 64 + lane] = o;
}

// ---- launch ----------------------------------------------------------------

static inline size_t align256(size_t x) { return (x + 255) & ~(size_t)255; }

extern "C" void kernel_launch(void* const* d_in, const int* in_sizes, int n_in,
                              void* d_out, int out_size, void* d_ws, size_t ws_size,
                              hipStream_t stream) {
    const float* x  = (const float*)d_in[0];
    const int*   ei = (const int*)d_in[1];
    const float* W1 = (const float*)d_in[2];
    const float* b1 = (const float*)d_in[3];
    const float* W2 = (const float*)d_in[4];
    const float* b2 = (const float*)d_in[5];
    const float* W3 = (const float*)d_in[6];
    const float* b3 = (const float*)d_in[7];

    int n = in_sizes[0] / FEAT;      // 100000
    int E = in_sizes[1] / 2;         // 1600000
    const int* src = ei;
    const int* dst = ei + E;

    // workspace carve-up (~59 MB)
    char* w = (char*)d_ws;
    int* counts  = (int*)w;                   w += align256((size_t)n * 4);
    int* indptr  = (int*)w;                   w += align256((size_t)(n + 1) * 4);
    int* cursor  = (int*)w;                   w += align256((size_t)n * 4);
    float* dinv  = (float*)w;                 w += align256((size_t)n * 4);
    int* ssrc    = (int*)w;                   w += align256((size_t)E * 4);
    float* hs    = (float*)w;                 w += align256((size_t)n * FEAT * 4);

    float* hbuf = (float*)d_out;             // inter-layer activations live in d_out

    hipMemsetAsync(counts, 0, (size_t)n * 4, stream);

    hist_kernel<<<(E + 255) / 256, 256, 0, stream>>>(dst, counts, E);
    scan_kernel<<<1, 1024, 0, stream>>>(counts, indptr, cursor, dinv, n, E);
    fill_kernel<<<(E + 255) / 256, 256, 0, stream>>>(src, dst, cursor, ssrc, E);

    for (int L = 0; L < 3; ++L) {
        const float* gin = (L == 0) ? x : hbuf;
        const float* WL  = (L == 0) ? W1 : (L == 1) ? W2 : W3;
        const float* bb  = (L == 0) ? b1 : (L == 1) ? b2 : b3;

        dim3 blk(32, 8);
        gemm_f32<<<n / 8, blk, 0, stream>>>(gin, WL, dinv, hs, n);
        agg_kernel<<<(n + 3) / 4, 256, 0, stream>>>(hs, indptr, ssrc, dinv, bb, hbuf, n, (L < 2) ? 1 : 0);
    }
}